// Round 9
// baseline (3182.299 us; speedup 1.0000x reference)
//
#include <hip/hip_runtime.h>
#include <math.h>

#define T_TOTAL   1000
#define BATCH     256
#define NH        256
#define NIN       85

static constexpr float SIGMA_C = 0.15811388300841897f;  // sqrt(2/0.2)*0.05
static constexpr float ALPHA_C = 0.2f;

using half4   = __attribute__((ext_vector_type(4))) _Float16;
using half8   = __attribute__((ext_vector_type(8))) _Float16;
using f32x4   = __attribute__((ext_vector_type(4))) float;

// workspace layout
#define GXEG_F    ((size_t)(T_TOTAL+1)*16*32*256)   // f32 gate preacts: [t][R][tau(32)][lane][4] = 525MB
#define GXEE_US   ((size_t)(T_TOTAL+1)*16*4096)     // f16 E tiles: [t][R][wv(4)][lane][16] = 131MB
#define WPACK_US  (4u*12u*8u*64u*8u)                // recurrent-weight B-fragments (f16 bits)
#define WXPACK_US (48u*3u*64u*8u)                   // x-weight B-fragments (K padded 85->96)

__device__ __forceinline__ unsigned short f2h(float f){
  _Float16 h = (_Float16)f;
  return __builtin_bit_cast(unsigned short, h);
}

__device__ __forceinline__ void gload_lds16(const void* g, void* l){
  __builtin_amdgcn_global_load_lds((const __attribute__((address_space(1))) void*)g,
                                   (__attribute__((address_space(3))) void*)l, 16, 0, 0);
}

// ---------------- k0: pack weights into MFMA B-fragment order (f16) ----------------
// wpack[w(4)][tile(12: r j=0..3, u j=0..3, c j=0..3)][kt(8)][lane(64)][j8]
//   tau = 4w + (tile&3); value = W[k = kt*32 + (l>>4)*8 + j8][col = 16*tau + (l&15)]
// wxpack[tau(48)][kt(3)][lane(64)][j(8)]   (k >= 85 zero-padded)
__global__ void k0_pack(const float* __restrict__ gk, const float* __restrict__ ck,
                        unsigned short* __restrict__ wpack, unsigned short* __restrict__ wxpack){
  int tid = blockIdx.x*256 + threadIdx.x;
  if (tid < (int)WPACK_US) {
    int j = tid & 7, l = (tid >> 3) & 63, kt = (tid >> 9) & 7, wt = tid >> 12;
    int w = wt / 12, tile = wt - 12*w;
    int jj = tile & 3, kind = tile >> 2;    // 0=r, 1=u, 2=c
    int lrow = l & 15, lquad = l >> 4;
    int k = kt*32 + lquad*8 + j;            // hidden index 0..255
    int tau = 4*w + jj;                     // n-tile 0..15
    float v;
    if (kind == 0)      v = gk[(size_t)(85 + k)*512 + 16*tau + lrow];
    else if (kind == 1) v = gk[(size_t)(85 + k)*512 + 256 + 16*tau + lrow];
    else                v = ck[(size_t)(85 + k)*256 + 16*tau + lrow];
    wpack[tid] = f2h(v);
  } else if (tid < (int)(WPACK_US + WXPACK_US)) {
    int f = tid - (int)WPACK_US;
    int j = f & 7, l = (f >> 3) & 63, r = f >> 9;   // r = tau*3 + kt
    int kt = r % 3, tau = r / 3;
    int lrow = l & 15, lquad = l >> 4;
    int k = kt*32 + lquad*8 + j;            // x index, pad >=85 -> 0
    float v = 0.0f;
    if (k < NIN) {
      if (tau < 32) v = gk[(size_t)k*512 + 16*tau + lrow];
      else          v = ck[(size_t)k*256 + 16*(tau-32) + lrow];
    }
    wxpack[f] = f2h(v);
  }
}

// ---------------- k1: gxe precompute, ONE dispatch over all T ----------------
// gates (tau<32) -> f32 gxe[t][R][tau][lane][4]
// E (tau>=32, tau'=tau-32) -> f16 gxeE[t][R][tau'>>2][lane][ (tau'&3)*4 + i ]
__global__ __launch_bounds__(256) void k1_gxe(const float* __restrict__ x, const float* __restrict__ nz,
                       const float* __restrict__ gb, const float* __restrict__ cb,
                       const unsigned short* __restrict__ wxpack, float* __restrict__ gxe,
                       unsigned short* __restrict__ gxeE){
  int R  = blockIdx.x;
  int t  = blockIdx.y;
  int tid = threadIdx.x;
  __shared__ _Float16 xA[16][104];           // 96 K (padded) + 8 pad
  {
    int r = tid >> 4, c0 = tid & 15;
    const float* xrow = x + ((size_t)t*BATCH + 16*R + r)*NIN;
    for (int c = c0; c < 96; c += 16)
      xA[r][c] = (_Float16)(c < NIN ? xrow[c] : 0.0f);
  }
  __syncthreads();
  int l = tid & 63, wv = tid >> 6;
  int lrow = l & 15, lquad = l >> 4;
  const half8* xA8 = (const half8*)xA;       // row stride 104 f16 = 13 half8
  half8 afr[3];
  #pragma unroll
  for (int kt = 0; kt < 3; ++kt)
    afr[kt] = xA8[lrow*13 + kt*4 + lquad];
  const half8* wx8 = (const half8*)wxpack;
  for (int u = 0; u < 12; ++u) {
    int tau = wv + 4*u;                      // balanced: each wave gets 4 cand tiles
    f32x4 acc;
    if (tau < 32) {
      float b = gb[16*tau + lrow];
      acc = (f32x4){b, b, b, b};
    } else {
      int nc = 16*(tau-32) + lrow;
      float b = cb[nc];
      #pragma unroll
      for (int i = 0; i < 4; ++i)
        acc[i] = fmaf(SIGMA_C, nz[((size_t)t*BATCH + 16*R + lquad*4 + i)*NH + nc], b);
    }
    #pragma unroll
    for (int kt = 0; kt < 3; ++kt)
      acc = __builtin_amdgcn_mfma_f32_16x16x32_f16(afr[kt], wx8[((size_t)tau*3 + kt)*64 + l], acc, 0, 0, 0);
    if (tau < 32) {
      *(f32x4*)(gxe + ((((size_t)t*16 + R)*32 + tau)*64 + (size_t)l)*4) = acc;
    } else {
      int tp = tau - 32, w2 = tp >> 2, jj = tp & 3;
      half4 o = {(_Float16)acc[0], (_Float16)acc[1], (_Float16)acc[2], (_Float16)acc[3]};
      *(half4*)(gxeE + (((size_t)t*16 + R)*4 + w2)*1024 + (size_t)l*16 + jj*4) = o;
    }
  }
}

// ---------------- k2: ONE persistent recurrent scan over all 1000 steps ----------------
// 16 WGs x 4 waves (256 thr, launch_bounds(256,1) => 1 wave/SIMD => 512-VGPR budget).
// WG R owns batch rows [16R,16R+16); wave w owns n-cols [64w,64w+64) (taus 4w..4w+3).
// Weights VGPR-resident: 12 tiles x 8 kt = 384 regs/wave; total demand ~495 < 512,
// so NO VGPR/AGPR split and NO shuttles (R4-R8 root cause). Plain MFMA intrinsics
// (compiler-managed hazards). cand = cx + (r .* h) @ Wc_h + sigma*n.
// Sync: 2x (lgkmcnt(0); s_barrier) per step; gate DMA guarded by counted vmcnt(18)
// (16 out stores + 2 E loads issued after the 8 DMAs); gst read only via asm.
__global__ __launch_bounds__(256, 1) void k2_rec(const float* __restrict__ hin,
                       const unsigned short* __restrict__ wpack,
                       const float* __restrict__ gxe,
                       const unsigned short* __restrict__ gxeE,
                       float* __restrict__ out){
  int R = blockIdx.x;
  int tid = threadIdx.x;
  int l = tid & 63, w = tid >> 6;
  int lrow = l & 15, lquad = l >> 4;

  __shared__ float    gst[4*8*256];          // [w][gate tile q(8: r j, u j)][lane][4] f32, 32KB
  __shared__ _Float16 hA[16][264];           // h f16  [row][n], stride 264
  __shared__ _Float16 rhA[16][264];          // r.*h f16, same layout

  { // init hA (256 threads x 16 elems)
    int r = tid >> 4, c0 = (tid & 15)*16;
    const float* hrow = hin + ((size_t)(16*R + r))*NH + c0;
    #pragma unroll
    for (int i = 0; i < 16; ++i)
      hA[r][c0+i] = (_Float16)hrow[i];
  }
  float hreg[4][4];                          // h f32, lane-private (rows lquad*4+i, cols 64w+16j+lrow)
  #pragma unroll
  for (int j = 0; j < 4; ++j)
    #pragma unroll
    for (int i = 0; i < 4; ++i)
      hreg[j][i] = hin[(size_t)(16*R + lquad*4 + i)*NH + 64*w + 16*j + lrow];

  // resident weight fragments: r,u,c x 4 taus x 8 kt  (384 VGPRs)
  half8 wr[4][8], wu[4][8], wc[4][8];
  const half8* wp8 = (const half8*)wpack;
  #pragma unroll
  for (int j = 0; j < 4; ++j)
    #pragma unroll
    for (int kt = 0; kt < 8; ++kt){
      wr[j][kt] = wp8[((w*12 + j    )*8 + kt)*64 + l];
      wu[j][kt] = wp8[((w*12 + 4 + j)*8 + kt)*64 + l];
      wc[j][kt] = wp8[((w*12 + 8 + j)*8 + kt)*64 + l];
    }

  // gate staging: q=j -> r-tile tau=4w+j ; q=4+j -> u-tile tau=16+4w+j
  const size_t gstep  = (size_t)16*32*256;   // floats per time step
  const float* gsrcR  = gxe + ((size_t)R*32 + 4*w)*256 + (size_t)l*4;
  const float* gsrcU  = gsrcR + (size_t)16*256;
  float* lbase = gst + (size_t)w*8*256;      // wave-uniform LDS dest
  unsigned sb_addr = (unsigned)(unsigned long long)(const void*)lbase + (unsigned)l*16u;
  // E sidecar: 2x half8 per step
  const half8* gE = (const half8*)(gxeE + (((size_t)R*4 + w)*64 + (size_t)l)*16);
  const size_t estep8 = (size_t)16*4*64*2;   // half8 units per time step

  // prologue: stage step-0 gates, load E(0); __syncthreads drains everything once
  #pragma unroll
  for (int j = 0; j < 4; ++j){
    gload_lds16(gsrcR + (size_t)j*256, lbase + j*256);
    gload_lds16(gsrcU + (size_t)j*256, lbase + (4+j)*256);
  }
  half8 eh0 = gE[0];
  half8 eh1 = gE[1];
  __syncthreads();

  const half8* hA8  = (const half8*)hA;      // row stride 33 half8
  const half8* rhA8 = (const half8*)rhA;
  float* outp = out + ((size_t)(16*R + lquad*4))*NH + 64*w + lrow;

  for (int t = 0; t < T_TOTAL; ++t) {
    // gate preacts: wait own DMA (counted), read gst (asm-only access)
    f32x4 accr[4], accu[4];
    asm volatile(
      "s_waitcnt vmcnt(18)\n\t"
      "ds_read_b128 %0, %8\n\t"
      "ds_read_b128 %1, %8 offset:1024\n\t"
      "ds_read_b128 %2, %8 offset:2048\n\t"
      "ds_read_b128 %3, %8 offset:3072\n\t"
      "ds_read_b128 %4, %8 offset:4096\n\t"
      "ds_read_b128 %5, %8 offset:5120\n\t"
      "ds_read_b128 %6, %8 offset:6144\n\t"
      "ds_read_b128 %7, %8 offset:7168\n\t"
      "s_waitcnt lgkmcnt(0)"
      : "=&v"(accr[0]), "=&v"(accr[1]), "=&v"(accr[2]), "=&v"(accr[3]),
        "=&v"(accu[0]), "=&v"(accu[1]), "=&v"(accu[2]), "=&v"(accu[3])
      : "v"(sb_addr) : "memory");
    // stage gates(t+1) into the same wave-private slots (slack row at t=999)
    #pragma unroll
    for (int j = 0; j < 4; ++j){
      gload_lds16(gsrcR + gstep + (size_t)j*256, lbase + j*256);
      gload_lds16(gsrcU + gstep + (size_t)j*256, lbase + (4+j)*256);
    }
    gsrcR += gstep; gsrcU += gstep;
    // phase A: h @ Wg_h  (8 tiles: r j, u j)
    #pragma unroll
    for (int kt = 0; kt < 8; ++kt){
      half8 af = hA8[lrow*33 + kt*4 + lquad];
      #pragma unroll
      for (int j = 0; j < 4; ++j){
        accr[j] = __builtin_amdgcn_mfma_f32_16x16x32_f16(af, wr[j][kt], accr[j], 0, 0, 0);
        accu[j] = __builtin_amdgcn_mfma_f32_16x16x32_f16(af, wu[j][kt], accu[j], 0, 0, 0);
      }
    }
    // ew1: u-gates -> packed f16 aug; r-gates -> rhA
    half4 haug[4];
    #pragma unroll
    for (int j = 0; j < 4; ++j)
      #pragma unroll
      for (int i = 0; i < 4; ++i){
        float eu = __expf(-accu[j][i]);
        haug[j][i] = (_Float16)(ALPHA_C * __builtin_amdgcn_rcpf(1.0f + eu));
      }
    #pragma unroll
    for (int j = 0; j < 4; ++j){
      int ncol = 64*w + 16*j + lrow;
      #pragma unroll
      for (int i = 0; i < 4; ++i){
        float er = __expf(-accr[j][i]);
        float rg = __builtin_amdgcn_rcpf(1.0f + er);
        rhA[lquad*4+i][ncol] = (_Float16)(rg * hreg[j][i]);
      }
    }
    asm volatile("s_waitcnt lgkmcnt(0)\n\ts_barrier" ::: "memory");  // rhA visible
    // phase B: (r.*h) @ Wc_h  (4 c-tiles)
    f32x4 accB[4];
    #pragma unroll
    for (int j = 0; j < 4; ++j) accB[j] = (f32x4){0.f,0.f,0.f,0.f};
    #pragma unroll
    for (int kt = 0; kt < 8; ++kt){
      half8 af = rhA8[lrow*33 + kt*4 + lquad];
      #pragma unroll
      for (int j = 0; j < 4; ++j)
        accB[j] = __builtin_amdgcn_mfma_f32_16x16x32_f16(af, wc[j][kt], accB[j], 0, 0, 0);
    }
    // ew2: cand -> tanh -> leaky update; publish new h; 16 out stores (never drained)
    #pragma unroll
    for (int j = 0; j < 4; ++j){
      int ncol = 64*w + 16*j + lrow;
      #pragma unroll
      for (int i = 0; i < 4; ++i){
        float ev = (j < 2) ? (float)eh0[(j&1)*4 + i] : (float)eh1[(j&1)*4 + i];
        float cand = accB[j][i] + ev;
        float e2 = __expf(2.0f*cand);
        float c  = (e2 - 1.0f)*__builtin_amdgcn_rcpf(e2 + 1.0f);
        float hold = hreg[j][i];
        float hnew = fmaf((float)haug[j][i], c - hold, hold);
        hreg[j][i] = hnew;
        hA[lquad*4+i][ncol] = (_Float16)hnew;
        outp[(size_t)i*NH + (size_t)j*16] = hnew;
      }
    }
    outp += (size_t)BATCH*NH;
    // E(t+1) into regs (after last use; the 2 loads in the vmcnt(18) window)
    gE += estep8;
    eh0 = gE[0];
    eh1 = gE[1];
    asm volatile("s_waitcnt lgkmcnt(0)\n\ts_barrier" ::: "memory");  // hA visible
  }
}

extern "C" void kernel_launch(void* const* d_in, const int* in_sizes, int n_in,
                              void* d_out, int out_size, void* d_ws, size_t ws_size,
                              hipStream_t stream) {
  (void)in_sizes; (void)n_in; (void)out_size; (void)ws_size;
  const float* x  = (const float*)d_in[0];
  const float* h0 = (const float*)d_in[1];
  const float* gk = (const float*)d_in[2];
  const float* gb = (const float*)d_in[3];
  const float* ck = (const float*)d_in[4];
  const float* cb = (const float*)d_in[5];
  const float* nz = (const float*)d_in[6];
  float* out = (float*)d_out;

  float* gxe = (float*)d_ws;                               // 525MB f32 gates
  unsigned short* gxeE   = (unsigned short*)(gxe + GXEG_F); // 131MB f16 E
  unsigned short* wpack  = gxeE + GXEE_US;
  unsigned short* wxpack = wpack + WPACK_US;

  k0_pack<<<1056, 256, 0, stream>>>(gk, ck, wpack, wxpack);
  k1_gxe<<<dim3(16, T_TOTAL), 256, 0, stream>>>(x, nz, gb, cb, wxpack, gxe, gxeE);
  k2_rec<<<16, 256, 0, stream>>>(h0, wpack, gxe, gxeE, out);
}

// Round 10
// 2130.415 us; speedup vs baseline: 1.4937x; 1.4937x over previous
//
#include <hip/hip_runtime.h>
#include <math.h>

#define T_TOTAL   1000
#define BATCH     256
#define NH        256
#define NIN       85

static constexpr float SIGMA_C = 0.15811388300841897f;  // sqrt(2/0.2)*0.05
static constexpr float ALPHA_C = 0.2f;

using half4   = __attribute__((ext_vector_type(4))) _Float16;
using half8   = __attribute__((ext_vector_type(8))) _Float16;
using f32x4   = __attribute__((ext_vector_type(4))) float;

// workspace layout (ushort units)
#define GXEG_US   ((size_t)(T_TOTAL+1)*16*8*64*16)  // f16 gate preacts [t][R][w][lane][16] = 262MB
#define GXEE_US   ((size_t)(T_TOTAL+1)*16*8*64*8)   // f16 E tiles      [t][R][w][lane][8]  = 131MB
#define WPACK_US  (8u*6u*8u*64u*8u)                 // recurrent-weight B-fragments (f16 bits)
#define WXPACK_US (48u*3u*64u*8u)                   // x-weight B-fragments (K padded 85->96)

__device__ __forceinline__ unsigned short f2h(float f){
  _Float16 h = (_Float16)f;
  return __builtin_bit_cast(unsigned short, h);
}

// ---------------- k0: pack weights into MFMA B-fragment order (f16) ----------------
// wpack[w(8)][tile(6: r0,r1,u0,u1,c0,c1)][kt(8)][lane(64)][j(8)]
//   tau = 2w + (tile&1); value = W[k = kt*32 + (l>>4)*8 + j][col = 16*tau + (l&15)]
__global__ void k0_pack(const float* __restrict__ gk, const float* __restrict__ ck,
                        unsigned short* __restrict__ wpack, unsigned short* __restrict__ wxpack){
  int tid = blockIdx.x*256 + threadIdx.x;
  if (tid < (int)WPACK_US) {
    int j = tid & 7, l = (tid >> 3) & 63, kt = (tid >> 9) & 7, wt = tid >> 12;
    int w = wt / 6, tile = wt - 6*w;
    int lrow = l & 15, lquad = l >> 4;
    int k = kt*32 + lquad*8 + j;            // hidden index 0..255
    int tau = 2*w + (tile & 1);             // n-tile 0..15
    int kind = tile >> 1;                   // 0=r, 1=u, 2=c
    float v;
    if (kind == 0)      v = gk[(size_t)(85 + k)*512 + 16*tau + lrow];
    else if (kind == 1) v = gk[(size_t)(85 + k)*512 + 256 + 16*tau + lrow];
    else                v = ck[(size_t)(85 + k)*256 + 16*tau + lrow];
    wpack[tid] = f2h(v);
  } else if (tid < (int)(WPACK_US + WXPACK_US)) {
    int f = tid - (int)WPACK_US;
    int j = f & 7, l = (f >> 3) & 63, r = f >> 9;   // r = tau*3 + kt
    int kt = r % 3, tau = r / 3;
    int lrow = l & 15, lquad = l >> 4;
    int k = kt*32 + lquad*8 + j;            // x index, pad >=85 -> 0
    float v = 0.0f;
    if (k < NIN) {
      if (tau < 32) v = gk[(size_t)k*512 + 16*tau + lrow];
      else          v = ck[(size_t)k*256 + 16*(tau-32) + lrow];
    }
    wxpack[f] = f2h(v);
  }
}

// ---------------- k1: gxe precompute, ONE dispatch over all T ----------------
// gates (tau<32): kind=tau>>4 (0=r,1=u), w=(tau&15)>>1, p=tau&1
//   -> f16 gxeG[t][R][w][lane][kind*8 + p*4 + i]
// E (tau>=32, e=tau-32): -> f16 gxeE[t][R][e>>1][lane][(e&1)*4 + i]
__global__ __launch_bounds__(256) void k1_gxe(const float* __restrict__ x, const float* __restrict__ nz,
                       const float* __restrict__ gb, const float* __restrict__ cb,
                       const unsigned short* __restrict__ wxpack,
                       unsigned short* __restrict__ gxeG, unsigned short* __restrict__ gxeE){
  int R  = blockIdx.x;
  int t  = blockIdx.y;
  int tid = threadIdx.x;
  __shared__ _Float16 xA[16][104];           // 96 K (padded) + 8 pad
  {
    int r = tid >> 4, c0 = tid & 15;
    const float* xrow = x + ((size_t)t*BATCH + 16*R + r)*NIN;
    for (int c = c0; c < 96; c += 16)
      xA[r][c] = (_Float16)(c < NIN ? xrow[c] : 0.0f);
  }
  __syncthreads();
  int l = tid & 63, wv = tid >> 6;
  int lrow = l & 15, lquad = l >> 4;
  const half8* xA8 = (const half8*)xA;       // row stride 104 f16 = 13 half8
  half8 afr[3];
  #pragma unroll
  for (int kt = 0; kt < 3; ++kt)
    afr[kt] = xA8[lrow*13 + kt*4 + lquad];
  const half8* wx8 = (const half8*)wxpack;
  for (int u = 0; u < 12; ++u) {
    int tau = wv + 4*u;                      // balanced: each wave gets 4 cand tiles
    f32x4 acc;
    if (tau < 32) {
      float b = gb[16*tau + lrow];
      acc = (f32x4){b, b, b, b};
    } else {
      int nc = 16*(tau-32) + lrow;
      float b = cb[nc];
      #pragma unroll
      for (int i = 0; i < 4; ++i)
        acc[i] = fmaf(SIGMA_C, nz[((size_t)t*BATCH + 16*R + lquad*4 + i)*NH + nc], b);
    }
    #pragma unroll
    for (int kt = 0; kt < 3; ++kt)
      acc = __builtin_amdgcn_mfma_f32_16x16x32_f16(afr[kt], wx8[((size_t)tau*3 + kt)*64 + l], acc, 0, 0, 0);
    half4 o = {(_Float16)acc[0], (_Float16)acc[1], (_Float16)acc[2], (_Float16)acc[3]};
    if (tau < 32) {
      int kind = tau >> 4, w2 = (tau & 15) >> 1, p = tau & 1;
      *(half4*)(gxeG + ((((size_t)t*16 + R)*8 + w2)*64 + (size_t)l)*16 + kind*8 + p*4) = o;
    } else {
      int e = tau - 32, w2 = e >> 1, p = e & 1;
      *(half4*)(gxeE + ((((size_t)t*16 + R)*8 + w2)*64 + (size_t)l)*8 + p*4) = o;
    }
  }
}

// ---------------- k2: ONE persistent recurrent scan over all 1000 steps ----------------
// 16 WGs x 8 waves (2 waves/SIMD). WG R owns rows [16R,16R+16); wave w owns cols [32w,32w+32).
// cand = cx + (r .* h) @ Wc_h + sigma*n  (r applied BEFORE the matmul).
// THIS ROUND: gate preacts & E go straight HBM->VGPR (f16, double-buffered one step
// ahead) — no LDS-DMA, no asm ds_reads, no counted-vmcnt machinery. DS pipe (the
// measured shared bottleneck, ~3400 cy/step/CU in R5-R9) keeps only the structural
// h/rh fragment broadcast. Plain MFMA intrinsics throughout (compiler hazards).
// Sync: exactly 2x (s_waitcnt lgkmcnt(0); s_barrier) per step; out stores never drain.
__global__ __launch_bounds__(512, 2) void k2_rec(const float* __restrict__ hin,
                       const unsigned short* __restrict__ wpack,
                       const unsigned short* __restrict__ gG,
                       const unsigned short* __restrict__ gE,
                       float* __restrict__ out){
  int R = blockIdx.x;
  int tid = threadIdx.x;
  int l = tid & 63, w = tid >> 6;
  int lrow = l & 15, lquad = l >> 4;

  __shared__ _Float16 hA[16][264];           // h f16  [row][n], stride 264
  __shared__ _Float16 rhA[16][264];          // r.*h f16, same layout

  { // init hA
    int r = tid >> 5, c0 = (tid & 31)*8;
    const float* hrow = hin + ((size_t)(16*R + r))*NH + c0;
    #pragma unroll
    for (int i = 0; i < 8; ++i)
      hA[r][c0+i] = (_Float16)hrow[i];
  }
  float hreg[2][4];                          // h f32, lane-private (rows lquad*4+i, cols 32w+16p+lrow)
  #pragma unroll
  for (int p = 0; p < 2; ++p)
    #pragma unroll
    for (int i = 0; i < 4; ++i)
      hreg[p][i] = hin[(size_t)(16*R + lquad*4 + i)*NH + 32*w + 16*p + lrow];

  // resident weight fragments (192 VGPRs)
  half8 wf[6][8];
  const half8* wp8 = (const half8*)wpack;
  #pragma unroll
  for (int tile = 0; tile < 6; ++tile)
    #pragma unroll
    for (int kt = 0; kt < 8; ++kt)
      wf[tile][kt] = wp8[((w*6 + tile)*8 + kt)*64 + l];

  // gate / E streams: per-lane 32B (gates) + 16B (E) per step, f16
  const half8* gg  = (const half8*)gG + (((size_t)R*8 + w)*64 + (size_t)l)*2;
  const size_t gstepG = (size_t)16*8*64*2;   // half8 units per time step
  const half8* gep = (const half8*)gE + (((size_t)R*8 + w)*64 + (size_t)l);
  const size_t estep = (size_t)16*8*64;      // half8 units per time step

  half8 g0 = gg[0], g1 = gg[1];  gg += gstepG;   // gates(0): [r p0..p1 | u p0..p1]
  half8 eh = gep[0];             gep += estep;   // E(0)
  __syncthreads();

  const half8* hA8  = (const half8*)hA;      // row stride 33 half8
  const half8* rhA8 = (const half8*)rhA;
  float* outp = out + ((size_t)(16*R + lquad*4))*NH + 32*w + lrow;

  for (int t = 0; t < T_TOTAL; ++t) {
    // acc init from prefetched gates (lane-private, no LDS)
    f32x4 accr[2], accu[2];
    #pragma unroll
    for (int p = 0; p < 2; ++p)
      #pragma unroll
      for (int i = 0; i < 4; ++i){
        accr[p][i] = (float)g0[p*4 + i];
        accu[p][i] = (float)g1[p*4 + i];
      }
    // prefetch gates(t+1) (slack slab at t=999); ~full step to cover HBM latency
    g0 = gg[0]; g1 = gg[1]; gg += gstepG;
    // phase A: h @ Wg_h  (tiles r0,r1,u0,u1)
    #pragma unroll
    for (int kt = 0; kt < 8; ++kt){
      half8 af = hA8[lrow*33 + kt*4 + lquad];
      #pragma unroll
      for (int p = 0; p < 2; ++p){
        accr[p] = __builtin_amdgcn_mfma_f32_16x16x32_f16(af, wf[p  ][kt], accr[p], 0, 0, 0);
        accu[p] = __builtin_amdgcn_mfma_f32_16x16x32_f16(af, wf[2+p][kt], accu[p], 0, 0, 0);
      }
    }
    // ew1: u-gates -> packed f16 aug; r-gates -> rhA
    half4 haug[2];
    #pragma unroll
    for (int p = 0; p < 2; ++p)
      #pragma unroll
      for (int i = 0; i < 4; ++i){
        float eu = __expf(-accu[p][i]);
        haug[p][i] = (_Float16)(ALPHA_C * __builtin_amdgcn_rcpf(1.0f + eu));
      }
    #pragma unroll
    for (int p = 0; p < 2; ++p){
      int ncol = 32*w + 16*p + lrow;
      #pragma unroll
      for (int i = 0; i < 4; ++i){
        float er = __expf(-accr[p][i]);
        float rg = __builtin_amdgcn_rcpf(1.0f + er);
        rhA[lquad*4+i][ncol] = (_Float16)(rg * hreg[p][i]);
      }
    }
    asm volatile("s_waitcnt lgkmcnt(0)\n\ts_barrier" ::: "memory");  // rhA visible
    // phase B: (r.*h) @ Wc_h  (tiles c0,c1)
    f32x4 accB[2];
    accB[0] = (f32x4){0.f,0.f,0.f,0.f};
    accB[1] = (f32x4){0.f,0.f,0.f,0.f};
    #pragma unroll
    for (int kt = 0; kt < 8; ++kt){
      half8 af = rhA8[lrow*33 + kt*4 + lquad];
      #pragma unroll
      for (int p = 0; p < 2; ++p)
        accB[p] = __builtin_amdgcn_mfma_f32_16x16x32_f16(af, wf[4+p][kt], accB[p], 0, 0, 0);
    }
    // ew2: cand -> tanh -> leaky update; publish new h; 16 out stores (never drained)
    #pragma unroll
    for (int p = 0; p < 2; ++p){
      int ncol = 32*w + 16*p + lrow;
      #pragma unroll
      for (int i = 0; i < 4; ++i){
        float cand = accB[p][i] + (float)eh[p*4 + i];
        float e2 = __expf(2.0f*cand);
        float c  = (e2 - 1.0f)*__builtin_amdgcn_rcpf(e2 + 1.0f);
        float hold = hreg[p][i];
        float hnew = fmaf((float)haug[p][i], c - hold, hold);
        hreg[p][i] = hnew;
        hA[lquad*4+i][ncol] = (_Float16)hnew;
        outp[(size_t)i*NH + (size_t)p*16] = hnew;
      }
    }
    outp += (size_t)BATCH*NH;
    // prefetch E(t+1) after last use of eh
    eh = gep[0]; gep += estep;
    asm volatile("s_waitcnt lgkmcnt(0)\n\ts_barrier" ::: "memory");  // hA visible
  }
}

extern "C" void kernel_launch(void* const* d_in, const int* in_sizes, int n_in,
                              void* d_out, int out_size, void* d_ws, size_t ws_size,
                              hipStream_t stream) {
  (void)in_sizes; (void)n_in; (void)out_size; (void)ws_size;
  const float* x  = (const float*)d_in[0];
  const float* h0 = (const float*)d_in[1];
  const float* gk = (const float*)d_in[2];
  const float* gb = (const float*)d_in[3];
  const float* ck = (const float*)d_in[4];
  const float* cb = (const float*)d_in[5];
  const float* nz = (const float*)d_in[6];
  float* out = (float*)d_out;

  unsigned short* gxeG   = (unsigned short*)d_ws;           // 262MB f16 gates
  unsigned short* gxeE   = gxeG + GXEG_US;                  // 131MB f16 E
  unsigned short* wpack  = gxeE + GXEE_US;
  unsigned short* wxpack = wpack + WPACK_US;

  k0_pack<<<1056, 256, 0, stream>>>(gk, ck, wpack, wxpack);
  k1_gxe<<<dim3(16, T_TOTAL), 256, 0, stream>>>(x, nz, gb, cb, wxpack, gxeG, gxeE);
  k2_rec<<<16, 512, 0, stream>>>(h0, wpack, gxeG, gxeE, out);
}